// Round 11
// baseline (150.506 us; speedup 1.0000x reference)
//
#include <hip/hip_runtime.h>

typedef short v8s __attribute__((ext_vector_type(8)));
typedef float v16f __attribute__((ext_vector_type(16)));
typedef unsigned v4u __attribute__((ext_vector_type(4)));

#define Wh   1024
#define Hh   512
#define HWh  (Wh * Hh)
#define Wlr  512
#define HWlr (Wlr * 256)
#define ITERS 4
#define NBLK  512         // 512 blocks x 8 waves x 4 iters x 32 px = 524288 px (1 row/block)

// 32x32x16 MFMA version: one A-fragment read (b128) serves 32 output rows ->
// per-pixel LDS weight traffic HALVED vs 16x16x32 (24 vs 48 b128 per 16 px).
// Fragment table: 54 frags x 512 shorts: L0:32 (4mt x 8k), L1:16 (2mt x 8k),
// L2:4 (1mt x 4k), L3:2 (zero-padded M 16->32). All staged in LDS (54 KiB).
#define NFRAG     54
#define LDS_BYTES (NFRAG * 1024)   // 55296

__device__ __forceinline__ unsigned short f2bf(float f) {
    union { float f; unsigned u; } v; v.f = f;
    unsigned r = v.u + 0x7FFFu + ((v.u >> 16) & 1u);  // RNE (prep kernel only)
    return (unsigned short)(r >> 16);
}
// hot-path pack: single-instruction packed f32->bf16 (RNE; dst.lo=a, dst.hi=b)
__device__ __forceinline__ unsigned pk2(float a, float b) {
    unsigned r;
    asm("v_cvt_pk_bf16_f32 %0, %1, %2" : "=v"(r) : "v"(a), "v"(b));
    return r;
}
__device__ __forceinline__ float leaky(float x) { return fmaxf(x, 0.01f * x); }

// relay: 32x32 C accumulator (16 regs) -> two B-frags of the next layer.
// C layout: col=lane&31 (pixel), row=(reg&3)+8*(reg>>2)+4*hi  [m74/m101].
// Lo half (regs 0..7)  -> k-step 2mt   (channels 32mt +    {0-3,8-11} + 4hi)
// Hi half (regs 8..15) -> k-step 2mt+1 (channels 32mt + 16+{0-3,8-11} + 4hi)
// Next layer's weights are K-permuted to match (cperm in prep kernel).
__device__ __forceinline__ v8s relayLo(const v16f& a) {
    v4u w;
    w[0] = pk2(leaky(a[0]), leaky(a[1]));
    w[1] = pk2(leaky(a[2]), leaky(a[3]));
    w[2] = pk2(leaky(a[4]), leaky(a[5]));
    w[3] = pk2(leaky(a[6]), leaky(a[7]));
    return __builtin_bit_cast(v8s, w);
}
__device__ __forceinline__ v8s relayHi(const v16f& a) {
    v4u w;
    w[0] = pk2(leaky(a[8]),  leaky(a[9]));
    w[1] = pk2(leaky(a[10]), leaky(a[11]));
    w[2] = pk2(leaky(a[12]), leaky(a[13]));
    w[3] = pk2(leaky(a[14]), leaky(a[15]));
    return __builtin_bit_cast(v8s, w);
}

// ---------- prep kernel: pack all 54 weight fragments into d_ws ----------
// A-frag layout (32x32x16): element j of lane (hi=l>>5, r=l&31) = W[row=..][k],
// row = mt*32 + r, k = t*16 + hi*8 + j (L0 identity) or cperm (L1..L3).
// cperm(t,hi,j) = 32*(t>>1) + 16*(t&1) + (j&3) + 8*(j>>2) + 4*hi  (bijective)
__global__ void prep_kernel(const float* __restrict__ w0g, const float* __restrict__ w1g,
                            const float* __restrict__ w2g, const float* __restrict__ w3g,
                            unsigned short* __restrict__ ws)
{
    const int f = blockIdx.x;     // 0..53
    const int l = threadIdx.x;    // 0..63
    const int r = l & 31, hi = l >> 5;
    unsigned short* dst = ws + f * 512 + l * 8;

    if (f < 32) {                 // L0: mt = f>>3, t = f&7, identity K (rep channels)
        int mt = f >> 3, t = f & 7;
        const float* src = w0g + (mt * 32 + r) * 128 + t * 16 + hi * 8;
#pragma unroll
        for (int j = 0; j < 8; ++j) dst[j] = f2bf(src[j]);
    } else if (f < 48) {          // L1: K-permuted for 32x32 register relay
        int g = f - 32, mt = g >> 3, t = g & 7;
        const float* row = w1g + (mt * 32 + r) * 128;
#pragma unroll
        for (int j = 0; j < 8; ++j)
            dst[j] = f2bf(row[32 * (t >> 1) + 16 * (t & 1) + (j & 3) + 8 * (j >> 2) + 4 * hi]);
    } else if (f < 52) {          // L2 (32x64): t = f-48, K-permuted
        int t = f - 48;
        const float* row = w2g + r * 64;
#pragma unroll
        for (int j = 0; j < 8; ++j)
            dst[j] = f2bf(row[32 * (t >> 1) + 16 * (t & 1) + (j & 3) + 8 * (j >> 2) + 4 * hi]);
    } else {                      // L3 (16x32): t = f-52, K-permuted, rows 16..31 zero-pad
        int t = f - 52;
#pragma unroll
        for (int j = 0; j < 8; ++j)
            dst[j] = (r < 16)
                ? f2bf(w3g[r * 32 + 16 * t + (j & 3) + 8 * (j >> 2) + 4 * hi])
                : (unsigned short)0;
    }
}

// 512-thread blocks, min-waves 2 (VGPR cap 256): the relay live set (~200 regs
// at 32-px width) spills under any tighter bound (R1/R2/R4 lessons). DO NOT TIGHTEN.
// Expected residency: 1 block/CU (8 waves) — fine: LDS-pipe work per CU is
// occupancy-independent, and that is the bottleneck being halved here.
__global__ __launch_bounds__(512, 2)
void cmfsm_kernel(const float* __restrict__ lr, const float* __restrict__ hr,
                  const unsigned short* __restrict__ ws,
                  const float* __restrict__ w4g, const float* __restrict__ w5g,
                  const float* __restrict__ t0g, const float* __restrict__ t1g,
                  const float* __restrict__ t2g, const float* __restrict__ fwg,
                  float* __restrict__ out)
{
    extern __shared__ unsigned short smem[];
    unsigned short* wfrag = smem;                    // 54*512 shorts

    const int tid  = threadIdx.x;
    const int lane = tid & 63;
    const int wv   = tid >> 6;    // 0..7
    const int n    = lane & 31;   // MFMA col (pixel)
    const int hi   = lane >> 5;   // k-half

    // ---- cheap prologue: coalesced 54KB copy d_ws -> LDS ----
    {
        const uint4* src = (const uint4*)ws;
        uint4* dst = (uint4*)smem;
#pragma unroll
        for (int e = 0; e < 7; ++e) {
            int idx = tid + e * 512;
            if (idx < (NFRAG * 1024 / 16)) dst[idx] = src[idx];
        }
    }

    // ---- fused layers 4+5: w45[r] = sum_j w5[j]*w4[j][ch], ch=(r&3)+8*(r>>2)+4hi ----
    float w45[8];
#pragma unroll
    for (int r = 0; r < 8; ++r) {
        const int ch = (r & 3) + 8 * (r >> 2) + 4 * hi;
        float s = 0.f;
#pragma unroll
        for (int j = 0; j < 8; ++j) s += w5g[j] * w4g[j * 16 + ch];
        w45[r] = s;
    }

    const int row = blockIdx.x;   // one image row per block

    // ---- weights2: 4 parity values; row parity block-uniform ----
    float w2e, w2o;
    {
        float tab[4];
#pragma unroll
        for (int yp = 0; yp < 2; ++yp)
#pragma unroll
            for (int xp = 0; xp < 2; ++xp) {
                float i0 = xp ? 1.f : -1.f;
                float i1 = yp ? 1.f : -1.f;
                float i2 = 1.41421356237309505f;
                float h0[3], h1[2];
                for (int o = 0; o < 3; ++o)
                    h0[o] = leaky(t0g[o*3+0]*i0 + t0g[o*3+1]*i1 + t0g[o*3+2]*i2);
                for (int o = 0; o < 2; ++o)
                    h1[o] = leaky(t1g[o*3+0]*h0[0] + t1g[o*3+1]*h0[1] + t1g[o*3+2]*h0[2]);
                tab[yp*2+xp] = t2g[0]*h1[0] + t2g[1]*h1[1];
            }
        const int yp = row & 1;
        w2e = yp ? tab[2] : tab[0];
        w2o = yp ? tab[3] : tab[1];
    }
    const float fa = fabsf(fwg[0]);
    const float fb = fabsf(fwg[1]);

    __syncthreads();   // wfrag ready; everything after is wave-private

    const unsigned short* WL = wfrag + lane * 8;     // A-frag read base

    // ---- per-lane global pointers: lane (hi,n) owns 16 ch of hr and lr ----
    // ch(c) = c<8 ? hi*8+c : 16+hi*8+(c-8); per-iter imm: hr +256 floats, lr +128
    const float* hrp[16];
    const float* lrp[16];
    {
        const int hbase = row * Wh + wv * 32 + n;
        const int lbase = (row >> 1) * Wlr + wv * 16 + (n >> 1);
#pragma unroll
        for (int c = 0; c < 16; ++c) {
            const int ch = (c < 8) ? (hi * 8 + c) : (16 + hi * 8 + (c - 8));
            hrp[c] = hr + (size_t)ch * HWh  + hbase;
            lrp[c] = lr + (size_t)ch * HWlr + lbase;
        }
    }

    const int obase = row * Wh + wv * 32 + n;

    const v16f z16 = (v16f){0.f,0.f,0.f,0.f,0.f,0.f,0.f,0.f,
                            0.f,0.f,0.f,0.f,0.f,0.f,0.f,0.f};

    // ---- software pipeline: preload iteration 0's staging values ----
    float h[16], l[16];
#pragma unroll
    for (int c = 0; c < 16; ++c) { h[c] = hrp[c][0]; l[c] = lrp[c][0]; }

#pragma unroll
    for (int it = 0; it < ITERS; ++it) {
        // ---- layer-0 B fragments (8 k-steps): lr, lr, hr, hr, prod, prod, sq, sq ----
        v4u f0, f1, f2, f3, f4, f5, f6, f7;
#pragma unroll
        for (int u = 0; u < 4; ++u) {
            float la = l[2*u], lb = l[2*u+1], ha = h[2*u], hb = h[2*u+1];
            float lA = l[8+2*u], lB = l[9+2*u], hA = h[8+2*u], hB = h[9+2*u];
            f0[u] = pk2(la, lb);
            f1[u] = pk2(lA, lB);
            f2[u] = pk2(ha, hb);
            f3[u] = pk2(hA, hB);
            f4[u] = pk2(la * ha, lb * hb);
            f5[u] = pk2(lA * hA, lB * hB);
            float d0 = la - ha, d1 = lb - hb, D0 = lA - hA, D1 = lB - hB;
            f6[u] = pk2(d0 * d0, d1 * d1);
            f7[u] = pk2(D0 * D0, D1 * D1);
        }
        v8s b[8] = { __builtin_bit_cast(v8s, f0), __builtin_bit_cast(v8s, f1),
                     __builtin_bit_cast(v8s, f2), __builtin_bit_cast(v8s, f3),
                     __builtin_bit_cast(v8s, f4), __builtin_bit_cast(v8s, f5),
                     __builtin_bit_cast(v8s, f6), __builtin_bit_cast(v8s, f7) };

        // ---- prefetch next iteration (all-immediate addressing, it static) ----
        if (it + 1 < ITERS) {
            const int ho = (it + 1) * 256;   // hr: imm 1024B steps
            const int lo = (it + 1) * 128;   // lr: imm 512B steps
#pragma unroll
            for (int c = 0; c < 16; ++c) {
                h[c] = hrp[c][ho];
                l[c] = lrp[c][lo];
            }
        }

        // ---- layer 0: 128 -> 128, 4 m-tiles of 32, relay per tile ----
        v8s c1[8];
#pragma unroll
        for (int mt = 0; mt < 4; ++mt) {
            v16f acc = z16;
#pragma unroll
            for (int t = 0; t < 8; ++t) {
                v8s a = *(const v8s*)(WL + (mt * 8 + t) * 512);
                acc = __builtin_amdgcn_mfma_f32_32x32x16_bf16(a, b[t], acc, 0, 0, 0);
            }
            c1[2 * mt]     = relayLo(acc);
            c1[2 * mt + 1] = relayHi(acc);
        }

        // ---- layer 1: 128 -> 64, 2 m-tiles ----
        v8s c2[4];
#pragma unroll
        for (int mt = 0; mt < 2; ++mt) {
            v16f acc = z16;
#pragma unroll
            for (int t = 0; t < 8; ++t) {
                v8s a = *(const v8s*)(WL + (32 + mt * 8 + t) * 512);
                acc = __builtin_amdgcn_mfma_f32_32x32x16_bf16(a, c1[t], acc, 0, 0, 0);
            }
            c2[2 * mt]     = relayLo(acc);
            c2[2 * mt + 1] = relayHi(acc);
        }

        // ---- layer 2: 64 -> 32, 1 m-tile, 4 k-steps ----
        v8s c3[2];
        {
            v16f acc = z16;
#pragma unroll
            for (int t = 0; t < 4; ++t) {
                v8s a = *(const v8s*)(WL + (48 + t) * 512);
                acc = __builtin_amdgcn_mfma_f32_32x32x16_bf16(a, c2[t], acc, 0, 0, 0);
            }
            c3[0] = relayLo(acc);
            c3[1] = relayHi(acc);
        }

        // ---- layer 3: 32 -> 16 (M zero-padded to 32), 2 k-steps ----
        {
            v16f acc = z16;
#pragma unroll
            for (int t = 0; t < 2; ++t) {
                v8s a = *(const v8s*)(WL + (52 + t) * 512);
                acc = __builtin_amdgcn_mfma_f32_32x32x16_bf16(a, c3[t], acc, 0, 0, 0);
            }
            // regs 0..7 hold the 16 real channels split across the hi pair
            float part = 0.f;
#pragma unroll
            for (int r = 0; r < 8; ++r) part += w45[r] * leaky(acc[r]);
            part += __shfl_xor(part, 32, 64);

            if (hi == 0) {
                const float w2v = (n & 1) ? w2o : w2e;
                out[obase + it * 256] = fa * part + fb * w2v;
            }
        }
    }
}

extern "C" void kernel_launch(void* const* d_in, const int* in_sizes, int n_in,
                              void* d_out, int out_size, void* d_ws, size_t ws_size,
                              hipStream_t stream) {
    const float* lr  = (const float*)d_in[0];
    const float* hr  = (const float*)d_in[1];
    const float* w0g = (const float*)d_in[2];
    const float* w1g = (const float*)d_in[3];
    const float* w2g = (const float*)d_in[4];
    const float* w3g = (const float*)d_in[5];
    const float* w4g = (const float*)d_in[6];
    const float* w5g = (const float*)d_in[7];
    const float* t0g = (const float*)d_in[8];
    const float* t1g = (const float*)d_in[9];
    const float* t2g = (const float*)d_in[10];
    const float* fwg = (const float*)d_in[11];
    float* out = (float*)d_out;
    unsigned short* ws = (unsigned short*)d_ws;   // needs 54*512*2 = 55296 B

    hipLaunchKernelGGL(prep_kernel, dim3(NFRAG), dim3(64), 0, stream,
                       w0g, w1g, w2g, w3g, ws);
    hipLaunchKernelGGL(cmfsm_kernel, dim3(NBLK), dim3(512), LDS_BYTES, stream,
                       lr, hr, ws, w4g, w5g, t0g, t1g, t2g, fwg, out);
}